// Round 3
// baseline (73.327 us; speedup 1.0000x reference)
//
#include <hip/hip_runtime.h>
#include <math.h>

#define B 64
#define F 128
#define T 64
#define D 256

// One kernel, one node. Block b owns batch b entirely: 1024 threads = 16 waves.
// Wave w, lane = t. Each thread: f = w + 16*i, i = 0..7 (8 sigmoids).
__global__ __launch_bounds__(1024) void fused_kernel(
    const float* __restrict__ x,
    const float* __restrict__ wconv, const float* __restrict__ bconv,
    const float* __restrict__ w1, const float* __restrict__ b1,
    const float* __restrict__ w2, const float* __restrict__ b2,
    float* __restrict__ out1, float* __restrict__ out2) {

    __shared__ float vatt_s[F * T];          // 32 KB [f][t]
    __shared__ float b1_s[F * (T + 1)];      // 33.3 KB [f][t], pad kills stride-64 aliasing
    __shared__ float s0red[16 * T], s1red[16 * T];   // 8 KB cross-wave partials
    __shared__ float part1[4 * D];           // 4 KB out1 partials
    __shared__ float A_s[T], C_s[T], P_s[T], Q_s[T];
    __shared__ float s0_s[T], s1_s[T], tatt_s[T];

    const int b    = blockIdx.x;
    const int tid  = threadIdx.x;
    const int w    = tid >> 6;      // wave 0..15
    const int lane = tid & 63;      // == t in phase 1

    const float* xb = x + b * F * T;

    // ---- hoist the 8 x-loads: independent HBM/L2 loads in flight over phase 0 ----
    float xv[8];
    #pragma unroll
    for (int i = 0; i < 8; ++i) xv[i] = xb[(w + 16 * i) * T + lane];   // coalesced (lane=t)

    // ---- stage b1 [T,F] -> b1_s transposed [f][t] (coalesced reads, conflict-free writes) ----
    #pragma unroll
    for (int k = 0; k < (T * F) / 1024; ++k) {       // 8 iters
        const int lin = tid + 1024 * k;
        const int t = lin >> 7;          // / F
        const int f = lin & (F - 1);
        b1_s[f * (T + 1) + t] = b1[lin];
    }

    // ---- phase 0: A/C/P/Q for this wave's 4 t's (float4 dot + wave64 reduce) ----
    // A[t]=dot(wconv[t],w1[t]) C[t]=dot(bconv[t],w1[t]) P[t]=dot(wconv[t],w2) Q[t]=dot(bconv[t],w2)
    {
        const float4 w2v = *reinterpret_cast<const float4*>(w2 + lane * 4);
        #pragma unroll
        for (int j = 0; j < 4; ++j) {
            const int t = w * 4 + j;
            const int base = t * D + lane * 4;
            const float4 wc  = *reinterpret_cast<const float4*>(wconv + base);
            const float4 bc  = *reinterpret_cast<const float4*>(bconv + base);
            const float4 w1v = *reinterpret_cast<const float4*>(w1 + base);
            float a  = wc.x*w1v.x + wc.y*w1v.y + wc.z*w1v.z + wc.w*w1v.w;
            float cc = bc.x*w1v.x + bc.y*w1v.y + bc.z*w1v.z + bc.w*w1v.w;
            float p  = wc.x*w2v.x + wc.y*w2v.y + wc.z*w2v.z + wc.w*w2v.w;
            float q  = bc.x*w2v.x + bc.y*w2v.y + bc.z*w2v.z + bc.w*w2v.w;
            #pragma unroll
            for (int off = 32; off > 0; off >>= 1) {    // wave64 reduce, 4 chains interleave
                a  += __shfl_down(a, off);
                cc += __shfl_down(cc, off);
                p  += __shfl_down(p, off);
                q  += __shfl_down(q, off);
            }
            if (lane == 0) { A_s[t] = a; C_s[t] = cc; P_s[t] = p; Q_s[t] = q; }
        }
    }
    __syncthreads();

    // ---- phase 1: vatt -> LDS + per-thread partial S0/S1 (t = lane) ----
    const float At = A_s[lane], Ct = C_s[lane];
    float s0 = 0.f, s1 = 0.f;
    #pragma unroll
    for (int i = 0; i < 8; ++i) {
        const int f = w + 16 * i;
        const float z = xv[i] * At + Ct + b1_s[f * (T + 1) + lane];
        const float v = 1.0f / (1.0f + __expf(-z));
        vatt_s[f * T + lane] = v;
        s0 += v;
        s1 += v * xv[i];
    }
    s0red[w * T + lane] = s0;
    s1red[w * T + lane] = s1;
    __syncthreads();

    // ---- phase 2: 16-wave reduce + temporal attention (t = tid for tid < 64) ----
    if (tid < T) {
        float S0 = 0.f, S1 = 0.f;
        #pragma unroll
        for (int ww = 0; ww < 16; ++ww) {
            S0 += s0red[ww * T + tid];
            S1 += s1red[ww * T + tid];
        }
        const float z = S1 * P_s[tid] + S0 * Q_s[tid] + b2[tid];
        s0_s[tid] = S0;
        s1_s[tid] = S1;
        tatt_s[tid] = 1.0f / (1.0f + __expf(-z));
    }
    __syncthreads();

    // ---- phase 3a: out1 partials — wg = tid>>8 covers 16 t's, d = tid&255 ----
    {
        const int wg = tid >> 8;
        const int d  = tid & (D - 1);
        float acc = 0.f;
        #pragma unroll
        for (int j = 0; j < 16; ++j) {
            const int t = wg * 16 + j;
            acc += tatt_s[t] * (wconv[t * D + d] * s1_s[t] + bconv[t * D + d] * s0_s[t]);
        }
        part1[wg * D + d] = acc;
    }

    // ---- phase 3b: out2[b,f,t] = vatt[f][t] * tatt[t] (before barrier: stores in flight) ----
    float* o2 = out2 + b * F * T;
    #pragma unroll
    for (int k = 0; k < (F * T) / 1024; ++k) {
        const int lin = tid + 1024 * k;
        o2[lin] = vatt_s[lin] * tatt_s[lin & (T - 1)];
    }
    __syncthreads();

    // ---- final: out1[b,d] = sum of 4 partials (no atomics, no memset) ----
    if (tid < D) {
        out1[b * D + tid] = part1[tid] + part1[D + tid] + part1[2 * D + tid] + part1[3 * D + tid];
    }
}

extern "C" void kernel_launch(void* const* d_in, const int* in_sizes, int n_in,
                              void* d_out, int out_size, void* d_ws, size_t ws_size,
                              hipStream_t stream) {
    const float* x     = (const float*)d_in[0];
    const float* wconv = (const float*)d_in[1];
    const float* bconv = (const float*)d_in[2];
    const float* w1    = (const float*)d_in[3];
    const float* b1    = (const float*)d_in[4];
    const float* w2    = (const float*)d_in[5];
    const float* b2    = (const float*)d_in[6];
    float* out = (float*)d_out;   // [B,D] then [B,F,T]

    fused_kernel<<<B, 1024, 0, stream>>>(x, wconv, bconv, w1, b1, w2, b2,
                                         out, out + B * D);
}